// Round 3
// baseline (3332.175 us; speedup 1.0000x reference)
//
#include <hip/hip_runtime.h>

// Problem: N=32768 rows, Din=1024, HID=512, K=1024 codes, 3 codebooks.
// d_out layout (float32):
//   H @ 0 [32768,512] | codes @ 16777216 [32768,3] | key_idx @ 16875520 [32]
//   token_emb @ 16875552 [32768,1536] | L_vq @ 67207200 scalar
// ws layout (floats): z @ 0 (32768*1536; h1 overlaps head, dead before z),
//   en @ 50331648 (3*1024*512), rn @ 51904512 (98304), alpha @ 52002816 (32768),
//   flag_cnt @ 52035584 (1 int), flags @ 52035585 (2*4096 ints)
//
// KEY NUMERICS INSIGHT (round 2 post-mortem): the reference computes
// dist = 2 - 2*sim in fp32, which QUANTIZES sim into bins of ulp(2)/2 =
// 1.19e-7, then argmin breaks the resulting exact ties toward the LOWER
// index. Both jax and np do this robustly. We must therefore argmin over
// the fp32-quantized dist (not raw sim), tie -> lowest code. The fp64
// rescue computes "quantized truth" for rows whose top-2 dist gap is tiny.

#define BM 128
#define BN 128
#define BK 16
#define MAXF 4096
#define TAU_DIST 2e-5f

#define CODES_OFF   16777216ULL
#define KEYIDX_OFF  16875520ULL
#define TOKEMB_OFF  16875552ULL
#define LVQ_OFF     67207200ULL

__device__ __forceinline__ unsigned flip_bits(float x) {
  unsigned b = __float_as_uint(x);
  return b ^ ((unsigned)((int)b >> 31) | 0x80000000u);
}
__device__ __forceinline__ float unflip_bits(unsigned ob) {
  unsigned b = (ob & 0x80000000u) ? (ob ^ 0x80000000u) : ~ob;
  return __uint_as_float(b);
}
// reference-exact dist: fl32(2 - 2*fl32(sim)); __f*_rn blocks fma contraction
__device__ __forceinline__ float qdist(float dot, float rnv) {
  float sim = __fmul_rn(dot, rnv);
  return __fadd_rn(2.0f, -__fmul_rn(2.0f, sim));
}
__device__ __forceinline__ float dist_of_key(unsigned long long q) {
  return unflip_bits(~(unsigned)(q >> 32));
}

// ---------------------------------------------------------------------------
// C[m,n] = act(A @ B + bias). grid=(M/128,N/128), block 256, 8x8 microtile.
template<int RELU>
__global__ __launch_bounds__(256)
void gemm_f32(const float* __restrict__ A, int lda,
              const float* __restrict__ B, int ldb,
              const float* __restrict__ bias,
              float* __restrict__ C, int ldc, int K)
{
  __shared__ float As[BK][BM + 4];
  __shared__ float Bs[BK][BN + 4];
  const int tid = threadIdx.x;
  const int tx = tid & 15, ty = tid >> 4;
  const long m0 = (long)blockIdx.x * BM;
  const long n0 = (long)blockIdx.y * BN;

  float acc[8][8];
#pragma unroll
  for (int i = 0; i < 8; i++)
#pragma unroll
    for (int j = 0; j < 8; j++) acc[i][j] = 0.f;

  for (int k0 = 0; k0 < K; k0 += BK) {
#pragma unroll
    for (int i = 0; i < 2; i++) {
      int f4 = tid + i * 256;
      int row = f4 >> 2, kc = (f4 & 3) * 4;
      float4 v = *(const float4*)(A + (m0 + row) * lda + k0 + kc);
      As[kc + 0][row] = v.x; As[kc + 1][row] = v.y;
      As[kc + 2][row] = v.z; As[kc + 3][row] = v.w;
    }
#pragma unroll
    for (int i = 0; i < 2; i++) {
      int f4 = tid + i * 256;
      int kr = f4 >> 5, c4 = (f4 & 31) * 4;
      *(float4*)&Bs[kr][c4] = *(const float4*)(B + (long)(k0 + kr) * ldb + n0 + c4);
    }
    __syncthreads();
#pragma unroll
    for (int kk = 0; kk < BK; kk++) {
      float a[8], b[8];
      *(float4*)&a[0] = *(const float4*)&As[kk][ty * 8];
      *(float4*)&a[4] = *(const float4*)&As[kk][ty * 8 + 4];
      *(float4*)&b[0] = *(const float4*)&Bs[kk][tx * 4];
      *(float4*)&b[4] = *(const float4*)&Bs[kk][64 + tx * 4];
#pragma unroll
      for (int i = 0; i < 8; i++)
#pragma unroll
        for (int j = 0; j < 8; j++)
          acc[i][j] = fmaf(a[i], b[j], acc[i][j]);
    }
    __syncthreads();
  }

  float bv[8];
#pragma unroll
  for (int j = 0; j < 8; j++) {
    int col = (j < 4) ? (tx * 4 + j) : (64 + tx * 4 + (j - 4));
    bv[j] = bias[n0 + col];
  }
#pragma unroll
  for (int i = 0; i < 8; i++) {
    float o[8];
#pragma unroll
    for (int j = 0; j < 8; j++) {
      float v = acc[i][j] + bv[j];
      if (RELU) v = fmaxf(v, 0.f);
      o[j] = v;
    }
    float* cp = C + (m0 + ty * 8 + i) * (long)ldc + n0;
    *(float4*)(cp + tx * 4) = *(const float4*)&o[0];
    *(float4*)(cp + 64 + tx * 4) = *(const float4*)&o[4];
  }
}

// ---------------------------------------------------------------------------
// Per (row-tile, codebook): argmin over quantized dist, tie -> lowest code.
// Flags rows with tiny top-2 dist gap for fp64 rescue. Writes codes, L_vq,
// token_emb gather.
__global__ __launch_bounds__(256)
void sim_argmax(const float* __restrict__ z,
                const float* __restrict__ en,
                const float* __restrict__ rn,
                float* __restrict__ out,
                float* __restrict__ lvq,
                int* __restrict__ flag_cnt,
                int* __restrict__ flags)
{
  __shared__ float As[BK][BM + 4];
  __shared__ float Bs[BK][BN + 4];
  __shared__ unsigned long long red[128][17];
  __shared__ float red2[128][17];
  __shared__ int bidx[128];
  __shared__ float dsum[128];

  const int tid = threadIdx.x;
  const int tx = tid & 15, ty = tid >> 4;
  const int c = blockIdx.y;
  const long m0 = (long)blockIdx.x * BM;
  const float* Az = z + (long)c * 512;
  const float* B = en + (long)c * 1024 * 512;

  float rrn[8];
#pragma unroll
  for (int i = 0; i < 8; i++)
    rrn[i] = rn[(long)c * 32768 + m0 + ty * 8 + i];

  unsigned long long best = 0ULL;   // key: (~flip(dist))<<32 | ~code; max = min dist, low code
  float bestd2 = 1e30f;             // second-best dist so far

  for (int ct = 0; ct < 8; ct++) {
    const int n0 = ct * 128;
    float acc[8][8];
#pragma unroll
    for (int i = 0; i < 8; i++)
#pragma unroll
      for (int j = 0; j < 8; j++) acc[i][j] = 0.f;

    for (int k0 = 0; k0 < 512; k0 += BK) {
#pragma unroll
      for (int i = 0; i < 2; i++) {
        int f4 = tid + i * 256;
        int row = f4 >> 2, kc = (f4 & 3) * 4;
        float4 v = *(const float4*)(Az + (m0 + row) * 1536 + k0 + kc);
        As[kc + 0][row] = v.x; As[kc + 1][row] = v.y;
        As[kc + 2][row] = v.z; As[kc + 3][row] = v.w;
      }
#pragma unroll
      for (int i = 0; i < 2; i++) {
        int f4 = tid + i * 256;
        int code = f4 >> 2, kc = (f4 & 3) * 4;
        float4 v = *(const float4*)(B + (long)(n0 + code) * 512 + k0 + kc);
        Bs[kc + 0][code] = v.x; Bs[kc + 1][code] = v.y;
        Bs[kc + 2][code] = v.z; Bs[kc + 3][code] = v.w;
      }
      __syncthreads();
#pragma unroll
      for (int kk = 0; kk < BK; kk++) {
        float a[8], b[8];
        *(float4*)&a[0] = *(const float4*)&As[kk][ty * 8];
        *(float4*)&a[4] = *(const float4*)&As[kk][ty * 8 + 4];
        *(float4*)&b[0] = *(const float4*)&Bs[kk][tx * 4];
        *(float4*)&b[4] = *(const float4*)&Bs[kk][64 + tx * 4];
#pragma unroll
        for (int i = 0; i < 8; i++)
#pragma unroll
          for (int j = 0; j < 8; j++)
            acc[i][j] = fmaf(a[i], b[j], acc[i][j]);
      }
      __syncthreads();
    }

    // per-thread top-2 by quantized dist (min; j ascending => code ascending,
    // strict < keeps the lowest code on exact ties)
#pragma unroll
    for (int i = 0; i < 8; i++) {
      float d1 = 1e30f, d2 = 1e30f; int bj = 0;
#pragma unroll
      for (int j = 0; j < 8; j++) {
        float d = qdist(acc[i][j], rrn[i]);
        if (d < d1) { d2 = d1; d1 = d; bj = j; }
        else if (d < d2) d2 = d;
      }
      int code = n0 + ((bj < 4) ? (tx * 4 + bj) : (64 + tx * 4 + (bj - 4)));
      red[ty * 8 + i][tx] =
          ((unsigned long long)(~flip_bits(d1)) << 32) | (unsigned)(~code);
      red2[ty * 8 + i][tx] = d2;
    }
    __syncthreads();
    if (tid < 128) {
      unsigned long long k1 = red[tid][0];
#pragma unroll
      for (int t = 1; t < 16; t++) {
        unsigned long long q = red[tid][t];
        k1 = (q > k1) ? q : k1;
      }
      float d2min = 1e30f;
#pragma unroll
      for (int t = 0; t < 16; t++) {
        unsigned long long q = red[tid][t];
        float cand = (q == k1) ? red2[tid][t] : dist_of_key(q);
        d2min = fminf(d2min, cand);
      }
      if (k1 > best) {
        float oldd = (best == 0ULL) ? 1e30f : dist_of_key(best);
        bestd2 = fminf(oldd, d2min);
        best = k1;
      } else {
        bestd2 = fminf(bestd2, dist_of_key(k1));
      }
    }
    __syncthreads();
  }

  if (tid < 128) {
    const long n = m0 + tid;
    const unsigned code = ~(unsigned)best;
    const float d1 = dist_of_key(best);
    out[CODES_OFF + (unsigned long long)n * 3 + c] = (float)code;
    bidx[tid] = (int)code;
    dsum[tid] = d1;                      // = 2 - 2*sim of winner (quantized)
    if (bestd2 - d1 < TAU_DIST) {        // near-tie (or boundary risk): rescue
      int slot = atomicAdd(flag_cnt, 1);
      if (slot < MAXF) { flags[2 * slot] = (int)n; flags[2 * slot + 1] = c; }
    }
  }
  __syncthreads();
  if (tid < 64) dsum[tid] += dsum[tid + 64];
  __syncthreads();
  if (tid < 64) {
    float s = dsum[tid];
#pragma unroll
    for (int off = 32; off; off >>= 1) s += __shfl_xor(s, off);
    if (tid == 0) atomicAdd(lvq, s * (0.25f / (32768.f * 512.f)));
  }
  for (int t = tid; t < 128 * 128; t += 256) {
    int r = t >> 7, d4 = (t & 127) * 4;
    float4 v = *(const float4*)(B + (long)bidx[r] * 512 + d4);
    *(float4*)(out + TOKEMB_OFF + (unsigned long long)(m0 + r) * 1536 + c * 512 + d4) = v;
  }
}

// ---------------------------------------------------------------------------
// fp64 rescue: recompute flagged (row, codebook) from h0 in double, then apply
// the reference's fp32 quantization (sim -> fp32 -> dist = 2-2*sim fp32) and
// argmin with lowest-index tie-break ("quantized truth"). Overwrites codes +
// token_emb. One block (256 thr) per flagged pair.
__global__ __launch_bounds__(256)
void rescue_fp64(const float* __restrict__ h0,
                 const float* __restrict__ W1, const float* __restrict__ b1,
                 const float* __restrict__ W2, const float* __restrict__ b2,
                 const float* __restrict__ Wm, const float* __restrict__ bm,
                 const float* __restrict__ Wt, const float* __restrict__ bt,
                 const float* __restrict__ Wp, const float* __restrict__ bp,
                 const float* __restrict__ cbm, const float* __restrict__ cbt,
                 const float* __restrict__ cbp,
                 const float* __restrict__ en,
                 const int* __restrict__ flag_cnt, const int* __restrict__ flags,
                 float* __restrict__ out)
{
  int nf = *flag_cnt; if (nf > MAXF) nf = MAXF;
  const int b = blockIdx.x;
  if (b >= nf) return;
  const int n = flags[2 * b];
  const int c = flags[2 * b + 1];
  const int t = threadIdx.x;

  __shared__ double s1[512];
  __shared__ double s2[512];
  __shared__ double sred[256];
  __shared__ float sd4[4];
  __shared__ int sk4[4];
  __shared__ double shz;

  const float* Wc = (c == 0) ? Wm : (c == 1) ? Wt : Wp;
  const float* bc = (c == 0) ? bm : (c == 1) ? bt : bp;
  const float* cb = (c == 0) ? cbm : (c == 1) ? cbt : cbp;
  const float* h0r = h0 + (size_t)n * 1024;

  { // h1 = relu(h0 @ W1 + b1)
    double a0 = 0.0, a1 = 0.0;
    for (int i = 0; i < 1024; i++) {
      double h = (double)h0r[i];
      a0 = fma(h, (double)W1[(size_t)i * 512 + t], a0);
      a1 = fma(h, (double)W1[(size_t)i * 512 + t + 256], a1);
    }
    s1[t]       = fmax(a0 + (double)b1[t], 0.0);
    s1[t + 256] = fmax(a1 + (double)b1[t + 256], 0.0);
  }
  __syncthreads();
  { // H = relu(h1 @ W2 + b2)
    double a0 = 0.0, a1 = 0.0;
    for (int i = 0; i < 512; i++) {
      double h = s1[i];
      a0 = fma(h, (double)W2[(size_t)i * 512 + t], a0);
      a1 = fma(h, (double)W2[(size_t)i * 512 + t + 256], a1);
    }
    s2[t]       = fmax(a0 + (double)b2[t], 0.0);
    s2[t + 256] = fmax(a1 + (double)b2[t + 256], 0.0);
  }
  __syncthreads();
  { // z = H @ Wc + bc
    double a0 = 0.0, a1 = 0.0;
    for (int i = 0; i < 512; i++) {
      double h = s2[i];
      a0 = fma(h, (double)Wc[(size_t)i * 512 + t], a0);
      a1 = fma(h, (double)Wc[(size_t)i * 512 + t + 256], a1);
    }
    __syncthreads();
    s1[t]       = a0 + (double)bc[t];
    s1[t + 256] = a1 + (double)bc[t + 256];
  }
  __syncthreads();
  sred[t] = s1[t] * s1[t] + s1[t + 256] * s1[t + 256];
  __syncthreads();
  for (int s = 128; s > 0; s >>= 1) {
    if (t < s) sred[t] += sred[t + s];
    __syncthreads();
  }
  if (t == 0) shz = 1.0 / sqrt(sred[0] + 1e-12);
  __syncthreads();
  const double rz = shz;

  // dist over all 1024 codes; wave wv handles k == wv (mod 4), k ascending
  const int wv = t >> 6, lane = t & 63;
  double zl[8];
#pragma unroll
  for (int m = 0; m < 8; m++) zl[m] = s1[lane * 8 + m];
  float bd = 1e30f; int bkk = 1 << 30;
  for (int j = 0; j < 256; j++) {
    int k = (j << 2) | wv;
    const float* cr = cb + (size_t)k * 512 + lane * 8;
    float4 c0 = *(const float4*)cr, c1 = *(const float4*)(cr + 4);
    double x0 = c0.x, x1 = c0.y, x2 = c0.z, x3 = c0.w;
    double x4 = c1.x, x5 = c1.y, x6 = c1.z, x7 = c1.w;
    double dt = zl[0]*x0 + zl[1]*x1 + zl[2]*x2 + zl[3]*x3
              + zl[4]*x4 + zl[5]*x5 + zl[6]*x6 + zl[7]*x7;
    double nc = x0*x0 + x1*x1 + x2*x2 + x3*x3 + x4*x4 + x5*x5 + x6*x6 + x7*x7;
#pragma unroll
    for (int off = 32; off; off >>= 1) {
      dt += __shfl_xor(dt, off);
      nc += __shfl_xor(nc, off);
    }
    double sim64 = dt * rz * (1.0 / sqrt(nc + 1e-12));
    float s32 = (float)sim64;
    float d32 = __fadd_rn(2.0f, -__fmul_rn(2.0f, s32));   // reference-exact quantization
    if (d32 < bd) { bd = d32; bkk = k; }                  // strict <: lowest k in residue
  }
  if (lane == 0) { sd4[wv] = bd; sk4[wv] = bkk; }
  __syncthreads();
  if (t == 0) {
    float d = sd4[0]; int k = sk4[0];
#pragma unroll
    for (int w = 1; w < 4; w++)
      if (sd4[w] < d || (sd4[w] == d && sk4[w] < k)) { d = sd4[w]; k = sk4[w]; }
    sk4[0] = k;
    out[CODES_OFF + (unsigned long long)n * 3 + c] = (float)k;
  }
  __syncthreads();
  const int fk = sk4[0];
  if (t < 128) {
    const float* er = en + ((size_t)c * 1024 + fk) * 512;
    float4 v = ((const float4*)er)[t];
    *(float4*)(out + TOKEMB_OFF + (unsigned long long)n * 1536 + c * 512 + t * 4) = v;
  }
}

// ---------------------------------------------------------------------------
__global__ __launch_bounds__(256)
void row_rnorm(const float* __restrict__ z, float* __restrict__ rn)
{
  const int lane = threadIdx.x & 63;
  const long r = (long)blockIdx.x * 4 + (threadIdx.x >> 6);
  const int cc = (int)(r >> 15), n = (int)(r & 32767);
  const float* p = z + (long)n * 1536 + cc * 512 + lane * 8;
  float4 v0 = *(const float4*)p, v1 = *(const float4*)(p + 4);
  float s = v0.x * v0.x + v0.y * v0.y + v0.z * v0.z + v0.w * v0.w
          + v1.x * v1.x + v1.y * v1.y + v1.z * v1.z + v1.w * v1.w;
#pragma unroll
  for (int off = 32; off; off >>= 1) s += __shfl_xor(s, off);
  if (lane == 0) rn[r] = 1.f / sqrtf(s + 1e-12f);
}

__global__ __launch_bounds__(256)
void cb_norm(const float* __restrict__ cbm, const float* __restrict__ cbt,
             const float* __restrict__ cbp, float* __restrict__ en)
{
  const int lane = threadIdx.x & 63;
  const long r = (long)blockIdx.x * 4 + (threadIdx.x >> 6);
  const int cc = (int)(r >> 10), k = (int)(r & 1023);
  const float* cb = (cc == 0) ? cbm : (cc == 1) ? cbt : cbp;
  const float* p = cb + (long)k * 512 + lane * 8;
  float4 v0 = *(const float4*)p, v1 = *(const float4*)(p + 4);
  float s = v0.x * v0.x + v0.y * v0.y + v0.z * v0.z + v0.w * v0.w
          + v1.x * v1.x + v1.y * v1.y + v1.z * v1.z + v1.w * v1.w;
#pragma unroll
  for (int off = 32; off; off >>= 1) s += __shfl_xor(s, off);
  float sc = 1.f / sqrtf(s + 1e-12f);
  v0.x *= sc; v0.y *= sc; v0.z *= sc; v0.w *= sc;
  v1.x *= sc; v1.y *= sc; v1.z *= sc; v1.w *= sc;
  float* q = en + (long)cc * 524288 + (long)k * 512 + lane * 8;
  *(float4*)q = v0; *(float4*)(q + 4) = v1;
}

__global__ __launch_bounds__(256)
void logits_alpha(const float* __restrict__ H, const float* __restrict__ Wk,
                  const float* __restrict__ bk, float* __restrict__ alpha)
{
  const int lane = threadIdx.x & 63;
  const long n = (long)blockIdx.x * 4 + (threadIdx.x >> 6);
  const float* p = H + n * 512 + lane * 8;
  const float* w = Wk + lane * 8;
  float4 a0 = *(const float4*)p, a1 = *(const float4*)(p + 4);
  float4 w0 = *(const float4*)w, w1 = *(const float4*)(w + 4);
  float s = a0.x * w0.x + a0.y * w0.y + a0.z * w0.z + a0.w * w0.w
          + a1.x * w1.x + a1.y * w1.y + a1.z * w1.z + a1.w * w1.w;
#pragma unroll
  for (int off = 32; off; off >>= 1) s += __shfl_xor(s, off);
  if (lane == 0) alpha[n] = 1.f / (1.f + expf(-(s + bk[0])));
}

__global__ __launch_bounds__(1024)
void topk32(const float* __restrict__ alpha, float* __restrict__ out)
{
  __shared__ unsigned long long sk[1024];
  const int tid = threadIdx.x;
  unsigned long long prev = ~0ULL;
  for (int it = 0; it < 32; it++) {
    unsigned long long best = 0;
#pragma unroll 4
    for (int i = tid; i < 32768; i += 1024) {
      unsigned long long key =
          ((unsigned long long)flip_bits(alpha[i]) << 32) | (unsigned)(~i);
      if (key < prev && key > best) best = key;
    }
    sk[tid] = best;
    __syncthreads();
    for (int s = 512; s > 0; s >>= 1) {
      if (tid < s) { unsigned long long q = sk[tid + s]; if (q > sk[tid]) sk[tid] = q; }
      __syncthreads();
    }
    unsigned long long sel = sk[0];
    __syncthreads();
    if (tid == 0) out[it] = (float)(~(unsigned)sel);
    prev = sel;
  }
}

extern "C" void kernel_launch(void* const* d_in, const int* in_sizes, int n_in,
                              void* d_out, int out_size, void* d_ws, size_t ws_size,
                              hipStream_t stream)
{
  (void)in_sizes; (void)n_in; (void)out_size; (void)ws_size;
  const float* h0  = (const float*)d_in[0];
  const float* W1  = (const float*)d_in[1];
  const float* b1  = (const float*)d_in[2];
  const float* W2  = (const float*)d_in[3];
  const float* b2  = (const float*)d_in[4];
  const float* Wm  = (const float*)d_in[5];
  const float* bm  = (const float*)d_in[6];
  const float* Wt  = (const float*)d_in[7];
  const float* bt  = (const float*)d_in[8];
  const float* Wp  = (const float*)d_in[9];
  const float* bp  = (const float*)d_in[10];
  const float* cbm = (const float*)d_in[11];
  const float* cbt = (const float*)d_in[12];
  const float* cbp = (const float*)d_in[13];
  const float* Wk  = (const float*)d_in[14];
  const float* bk  = (const float*)d_in[15];
  float* out = (float*)d_out;
  float* ws  = (float*)d_ws;

  float* h1 = ws;                    // [32768,512], dead before z written
  float* z  = ws;                    // [32768,1536]
  float* en = ws + 50331648ULL;      // [3,1024,512]
  float* rn = ws + 51904512ULL;      // [3*32768]
  float* al = ws + 52002816ULL;      // [32768]
  int* flag_cnt = (int*)(ws + 52035584ULL);
  int* flags    = (int*)(ws + 52035585ULL);  // [MAXF][2]
  float* H  = out;
  float* lvq = out + LVQ_OFF;

  hipMemsetAsync(lvq, 0, sizeof(float), stream);
  hipMemsetAsync(flag_cnt, 0, sizeof(int), stream);

  gemm_f32<1><<<dim3(256, 4), 256, 0, stream>>>(h0, 1024, W1, 512, b1, h1, 512, 1024);
  gemm_f32<1><<<dim3(256, 4), 256, 0, stream>>>(h1, 512,  W2, 512, b2, H,  512, 512);
  gemm_f32<0><<<dim3(256, 4), 256, 0, stream>>>(H, 512, Wm, 512, bm, z + 0,    1536, 512);
  gemm_f32<0><<<dim3(256, 4), 256, 0, stream>>>(H, 512, Wt, 512, bt, z + 512,  1536, 512);
  gemm_f32<0><<<dim3(256, 4), 256, 0, stream>>>(H, 512, Wp, 512, bp, z + 1024, 1536, 512);

  row_rnorm<<<24576, 256, 0, stream>>>(z, rn);
  cb_norm<<<768, 256, 0, stream>>>(cbm, cbt, cbp, en);
  sim_argmax<<<dim3(256, 3), 256, 0, stream>>>(z, en, rn, out, lvq, flag_cnt, flags);
  rescue_fp64<<<MAXF, 256, 0, stream>>>(h0, W1, b1, W2, b2, Wm, bm, Wt, bt, Wp, bp,
                                        cbm, cbt, cbp, en, flag_cnt, flags, out);
  logits_alpha<<<8192, 256, 0, stream>>>(H, Wk, bk, al);
  topk32<<<1, 1024, 0, stream>>>(al, out + KEYIDX_OFF);
}